// Round 10
// baseline (250.494 us; speedup 1.0000x reference)
//
#include <hip/hip_runtime.h>
#include <stdint.h>

// GIN conv: agg = segment_sum(val * x[col], row); h=(1+eps)x+agg;
// h=relu(h@W1+b1); h=relu(h@W2+b2); out=relu(h+bias).
// R12: revert R11 agg+mlp fusion (barrier after variable-degree work =
// +20% block-tail stall). Instead fuse k_bucket+k_agg -> k_buckagg:
// the barrier sits BETWEEN uniform CSR-build and per-wave-independent
// aggregation; edge list never leaves LDS (kills es 12.8MB wr + 12.8MB rd
// + rowptr round-trip + one dispatch). k_mlp = verified R10 version.

static constexpr int NN = 100000;
static constexpr int NE = 1600000;
static constexpr int NB = 392;    // buckets of 256 rows
static constexpr int EPB = 4096;  // edges per partition block
static constexpr int PB = (NE + EPB - 1) / EPB;  // 391
static constexpr int BCAP = 8192; // per-bucket edge capacity (avg 4082, 64 sigma)
static constexpr int NCVT = (NN * 32) / 1024;    // 3125 cvt blocks
static constexpr int NWB = 16;    // weight-convert blocks

typedef float f32x4 __attribute__((ext_vector_type(4)));
typedef short s16x8 __attribute__((ext_vector_type(8)));

__device__ __forceinline__ uint16_t f2bf(float f) {
  uint32_t u = __float_as_uint(f);
  u += 0x7fffu + ((u >> 16) & 1u);   // round-to-nearest-even
  return (uint16_t)(u >> 16);
}
__device__ __forceinline__ float2 bf2f(uint32_t w) {
  float2 r;
  r.x = __uint_as_float(w << 16);
  r.y = __uint_as_float(w & 0xffff0000u);
  return r;
}

// inclusive Hillis-Steele scan over first WIDTH entries of s0/s1.
// ALL threads of the block must call (barriers inside).
template <int WIDTH>
__device__ __forceinline__ int* scan_inc(int* s0, int* s1, int tid) {
  int* pin = s0;
  int* pout = s1;
  for (int off = 1; off < WIDTH; off <<= 1) {
    if (tid < WIDTH) pout[tid] = pin[tid] + ((tid >= off) ? pin[tid - off] : 0);
    __syncthreads();
    int* tmp = pin; pin = pout; pout = tmp;
  }
  return pin;
}

// ------- fused prep: [0,PB) edge partition | [PB,PB+NCVT) x->bf16 |
//         [PB+NCVT, +NWB) W1/W2 transpose->bf16 ---------------------------
__global__ __launch_bounds__(1024) void k_prep(const float* __restrict__ x,
                                               uint32_t* __restrict__ xb,
                                               const int* __restrict__ erow,
                                               const int* __restrict__ ecol,
                                               const float* __restrict__ eval,
                                               int2* __restrict__ part,
                                               int* __restrict__ runstart,
                                               const float* __restrict__ W1,
                                               const float* __restrict__ W2,
                                               uint32_t* __restrict__ wbp) {
  __shared__ int hist[NB];
  __shared__ int cur[NB];
  __shared__ int s0[512], s1[512];
  __shared__ int2 stage[EPB];
  int t = threadIdx.x;
  int bid = blockIdx.x;

  if (bid >= PB) {
    int cid = bid - PB;
    if (cid < NCVT) {
      // ---- x -> packed bf16 pairs ----
      int i = cid * 1024 + t;
      if (i < NN * 32) {
        float4 v = ((const float4*)x)[i];
        uint2 o;
        o.x = (uint32_t)f2bf(v.x) | ((uint32_t)f2bf(v.y) << 16);
        o.y = (uint32_t)f2bf(v.z) | ((uint32_t)f2bf(v.w) << 16);
        ((uint2*)xb)[i] = o;
      }
    } else {
      // ---- weight transpose: wb[m][n*128+k] = bf16(Wm[k*128+n]) ----
      int flat = (cid - NCVT) * 1024 + t;  // [0, 16384)
      int m = flat >> 13;                  // 0: W1, 1: W2
      int p = flat & 8191;
      int n = p >> 6;
      int k = (p & 63) * 2;
      const float* Wm = m ? W2 : W1;
      uint32_t lo = f2bf(Wm[k * 128 + n]);
      uint32_t hi = f2bf(Wm[(k + 1) * 128 + n]);
      wbp[(size_t)m * 8192 + n * 64 + (p & 63)] = lo | (hi << 16);
    }
    return;
  }

  // ---- edge partition into NB buckets (one block per EPB edges) ----
  int base = bid * EPB;
  int cnt = min(EPB, NE - base);

  if (t < NB) hist[t] = 0;
  __syncthreads();

  int pb[4], pk[4], pv[4];
  #pragma unroll
  for (int j = 0; j < 4; ++j) {
    int i = t + j * 1024;
    pb[j] = -1;
    if (i < cnt) {
      int e = base + i;
      int r = erow[e];
      int b = r >> 8;
      pb[j] = b;
      pk[j] = ecol[e] | ((r & 255) << 17);
      pv[j] = __float_as_int(eval[e]);
      atomicAdd(&hist[b], 1);
    }
  }
  __syncthreads();

  if (t < 512) s0[t] = (t < NB) ? hist[t] : 0;
  __syncthreads();
  int* inc = scan_inc<512>(s0, s1, t);

  if (t < NB) {
    int h = hist[t];
    int st = inc[t] - h;  // exclusive
    cur[t] = st;
    runstart[bid * (NB + 1) + t] = st;
  }
  if (t == 0) runstart[bid * (NB + 1) + NB] = cnt;
  __syncthreads();

  #pragma unroll
  for (int j = 0; j < 4; ++j) {
    if (pb[j] >= 0) {
      int off = atomicAdd(&cur[pb[j]], 1);
      stage[off] = int2{pk[j], pv[j]};
    }
  }
  __syncthreads();

  for (int i = t; i < cnt; i += 1024) part[base + i] = stage[i];
}

// ------- fused per-bucket CSR build + aggregate (one block per bucket) -----
// Phase 1 (uniform): gather bucket edges from part into LDS stage via
// binsearch; row-histogram; scans -> rps (row starts, bucket-local).
// barrier. Phase 2 (per-wave independent, NO barrier after): 16 waves x
// 16 nodes; SGPR edge stream from LDS (ds_read + readfirstlane); 16-batch
// masked gather (masked slots reuse scol[0]); h -> hb global (bf16).
__global__ __launch_bounds__(1024) void k_buckagg(const uint32_t* __restrict__ xb,
                                                  const int2* __restrict__ part,
                                                  const int* __restrict__ runstart,
                                                  const float* __restrict__ eps,
                                                  uint32_t* __restrict__ hb,
                                                  int nrows) {
  __shared__ int cum[PB + 1];
  __shared__ int rbas[PB];
  __shared__ int hist[256];
  __shared__ int rps[256];
  __shared__ int cur[256];
  __shared__ int s0[512], s1[512];
  __shared__ int2 stage[BCAP];
  int b = blockIdx.x, t = threadIdx.x;

  int len = 0;
  if (t < PB) {
    int rs = runstart[t * (NB + 1) + b];
    int re = runstart[t * (NB + 1) + b + 1];
    len = re - rs;
    rbas[t] = t * EPB + rs;
  }
  __syncthreads();
  if (t < 512) s0[t] = (t < PB) ? len : 0;
  __syncthreads();
  int* inc1 = scan_inc<512>(s0, s1, t);
  if (t < PB) cum[t] = inc1[t] - len;
  if (t == 0) cum[PB] = inc1[PB - 1];
  if (t < 256) hist[t] = 0;
  __syncthreads();

  int total = cum[PB];

  // pass 1: gather edges (binary search run), histogram rows-in-bucket
  int pk[8], pv[8];
  #pragma unroll
  for (int j = 0; j < 8; ++j) {
    int s = t + j * 1024;
    pk[j] = -1;
    if (s < total) {
      int lo = 0, hi = PB;  // invariant: cum[lo] <= s < cum[hi]
      while (hi - lo > 1) {
        int mid = (lo + hi) >> 1;
        if (cum[mid] <= s) lo = mid; else hi = mid;
      }
      int2 ev = part[rbas[lo] + (s - cum[lo])];
      pk[j] = ev.x; pv[j] = ev.y;
      atomicAdd(&hist[ev.x >> 17], 1);
    }
  }
  __syncthreads();

  if (t < 256) s0[t] = hist[t];
  __syncthreads();
  int* inc2 = scan_inc<256>(s0, s1, t);
  if (t < 256) {
    int ex = inc2[t] - hist[t];
    rps[t] = ex;
    cur[t] = ex;
  }
  __syncthreads();

  // pass 2: ticket-scatter into LDS stage (bucket-local offsets);
  // after this, cur[t] == rps[t] + hist[t] == row-end.
  #pragma unroll
  for (int j = 0; j < 8; ++j) {
    if (pk[j] >= 0) {
      int rib = pk[j] >> 17;
      int off = atomicAdd(&cur[rib], 1);
      if (off < BCAP) stage[off] = int2{pk[j] & 0x1FFFF, pv[j]};
      // off >= BCAP statistically impossible (needs bucket total > 8192)
    }
  }
  __syncthreads();

  // ---- phase 2: aggregate 16 nodes per wave (independent, no barrier) ----
  int wv = t >> 6, lane = t & 63;
  float e = 1.0f + eps[0];
  for (int i = 0; i < 16; ++i) {
    int tr = wv * 16 + i;            // local row in bucket
    int node = b * 256 + tr;
    if (node >= nrows) break;        // trailing buckets only
    float2 h = bf2f(xb[(size_t)node * 64 + lane]);
    h.x *= e; h.y *= e;
    int beg = __builtin_amdgcn_readfirstlane(rps[tr]);
    int end = __builtin_amdgcn_readfirstlane(cur[tr]);
    for (int k = beg; k < end; k += 16) {
      int scol[16]; float sval[16];
      {
        int2 ev0 = stage[k];  // j=0 always live (k < end)
        scol[0] = __builtin_amdgcn_readfirstlane(ev0.x);
        sval[0] = __int_as_float(__builtin_amdgcn_readfirstlane(ev0.y));
      }
      #pragma unroll
      for (int j = 1; j < 16; ++j) {
        int2 ev = stage[k + j];  // in-stage slack; masked values discarded
        int c = __builtin_amdgcn_readfirstlane(ev.x);
        int vb = __builtin_amdgcn_readfirstlane(ev.y);
        bool live = (k + j < end);
        scol[j] = live ? c : scol[0];  // masked: slot-0 line -> L1 hit
        sval[j] = live ? __int_as_float(vb) : 0.0f;
      }
      uint32_t xw[16];
      #pragma unroll
      for (int j = 0; j < 16; ++j)
        xw[j] = xb[((size_t)scol[j] << 6) + lane];
      #pragma unroll
      for (int j = 0; j < 16; ++j) {
        float2 xv = bf2f(xw[j]);
        h.x = fmaf(sval[j], xv.x, h.x);
        h.y = fmaf(sval[j], xv.y, h.y);
      }
    }
    hb[(size_t)node * 64 + lane] = (uint32_t)f2bf(h.x) | ((uint32_t)f2bf(h.y) << 16);
  }
}

// ---------------- fused 2-layer MFMA MLP: [64,128] rows per block ----------
// out = relu(relu(relu(h@W1+b1)@W2+b2)+bias). Weights arrive pre-transposed
// bf16 (wb[n*128+k]); staged into LDS stride-136 with conflict-free 16B
// vector copies. Interlayer h1 kept in LDS bf16. 3 blocks/CU.
__global__ __launch_bounds__(256, 3) void k_mlp(const uint16_t* __restrict__ A,
                                                const uint16_t* __restrict__ wb,
                                                const float* __restrict__ b1,
                                                const float* __restrict__ b2,
                                                const float* __restrict__ bias,
                                                float* __restrict__ out, int nrows) {
  __shared__ uint16_t wt[128 * 136];
  __shared__ uint16_t h1[64 * 136];
  int tid = threadIdx.x;

  // stage W1^T (bf16): 2048 16B-chunks, 8 iters, conflict-free
  #pragma unroll
  for (int it = 0; it < 8; ++it) {
    int c = tid + it * 256;          // chunk id 0..2047
    int r = c >> 4, cc = c & 15;
    *(uint4*)&wt[r * 136 + cc * 8] = *(const uint4*)&wb[r * 128 + cc * 8];
  }
  __syncthreads();

  int wv = tid >> 6, l = tid & 63;
  int m16 = l & 15, qg = l >> 4;
  int r0 = blockIdx.x * 64 + wv * 16;  // wave's 16-row tile
  int arow = r0 + m16;
  if (arow >= nrows) arow = nrows - 1;  // clamp; stores guarded

  f32x4 acc[8];
  #pragma unroll
  for (int n0 = 0; n0 < 8; ++n0) acc[n0] = f32x4{0.f, 0.f, 0.f, 0.f};

  #pragma unroll
  for (int k0 = 0; k0 < 128; k0 += 32) {
    s16x8 a = *(const s16x8*)(A + (size_t)arow * 128 + k0 + qg * 8);
    #pragma unroll
    for (int n0 = 0; n0 < 8; ++n0) {
      s16x8 bfr = *(const s16x8*)(&wt[(n0 * 16 + m16) * 136 + k0 + qg * 8]);
      acc[n0] = __builtin_amdgcn_mfma_f32_16x16x32_bf16(a, bfr, acc[n0], 0, 0, 0);
    }
  }

  // epilogue 1: relu(acc + b1) -> h1 LDS (bf16). C/D: col=lane&15, row=qg*4+j
  #pragma unroll
  for (int n0 = 0; n0 < 8; ++n0) {
    int col = n0 * 16 + m16;
    float bb = b1[col];
    #pragma unroll
    for (int j = 0; j < 4; ++j) {
      int lr = wv * 16 + qg * 4 + j;
      h1[lr * 136 + col] = f2bf(fmaxf(acc[n0][j] + bb, 0.0f));
    }
  }
  __syncthreads();

  // stage W2^T
  #pragma unroll
  for (int it = 0; it < 8; ++it) {
    int c = tid + it * 256;
    int r = c >> 4, cc = c & 15;
    *(uint4*)&wt[r * 136 + cc * 8] = *(const uint4*)&wb[16384 + r * 128 + cc * 8];
  }
  #pragma unroll
  for (int n0 = 0; n0 < 8; ++n0) acc[n0] = f32x4{0.f, 0.f, 0.f, 0.f};
  __syncthreads();

  #pragma unroll
  for (int k0 = 0; k0 < 128; k0 += 32) {
    s16x8 a = *(const s16x8*)(&h1[(wv * 16 + m16) * 136 + k0 + qg * 8]);
    #pragma unroll
    for (int n0 = 0; n0 < 8; ++n0) {
      s16x8 bfr = *(const s16x8*)(&wt[(n0 * 16 + m16) * 136 + k0 + qg * 8]);
      acc[n0] = __builtin_amdgcn_mfma_f32_16x16x32_bf16(a, bfr, acc[n0], 0, 0, 0);
    }
  }

  // epilogue 2: relu(relu(acc + b2) + bias) -> out (fp32)
  #pragma unroll
  for (int n0 = 0; n0 < 8; ++n0) {
    int col = n0 * 16 + m16;
    float bb = b2[col];
    float b3 = bias[col];
    #pragma unroll
    for (int j = 0; j < 4; ++j) {
      int row = r0 + qg * 4 + j;
      if (row < nrows) {
        float v = fmaxf(fmaxf(acc[n0][j] + bb, 0.0f) + b3, 0.0f);
        out[(size_t)row * 128 + col] = v;
      }
    }
  }
}

extern "C" void kernel_launch(void* const* d_in, const int* in_sizes, int n_in,
                              void* d_out, int out_size, void* d_ws, size_t ws_size,
                              hipStream_t stream) {
  const float* x    = (const float*)d_in[0];
  const int*   erow = (const int*)d_in[1];
  const int*   ecol = (const int*)d_in[2];
  const float* eval = (const float*)d_in[3];
  const float* W1   = (const float*)d_in[4];
  const float* b1   = (const float*)d_in[5];
  const float* W2   = (const float*)d_in[6];
  const float* b2   = (const float*)d_in[7];
  const float* eps  = (const float*)d_in[8];
  const float* bias = (const float*)d_in[9];

  char* w = (char*)d_ws;
  size_t off = 0;
  auto take = [&](size_t bytes) -> void* {
    void* p = w + off;
    off = (off + bytes + 255) & ~(size_t)255;
    return p;
  };
  uint32_t* xb     = (uint32_t*)take((size_t)NN * 64 * 4);   // bf16 x, packed
  uint32_t* hb     = (uint32_t*)take((size_t)NN * 64 * 4);   // bf16 h, packed
  int2*     part   = (int2*)take((size_t)NE * 8);
  int*      runst  = (int*)take((size_t)PB * (NB + 1) * 4);
  uint32_t* wb     = (uint32_t*)take((size_t)2 * 8192 * 4);  // W1^T,W2^T bf16
  (void)ws_size;

  k_prep<<<PB + NCVT + NWB, 1024, 0, stream>>>(x, xb, erow, ecol, eval, part,
                                               runst, W1, W2, wb);
  k_buckagg<<<NB, 1024, 0, stream>>>(xb, part, runst, eps, hb, NN);
  k_mlp<<<(NN + 63) / 64, 256, 0, stream>>>((const uint16_t*)hb,
                                            (const uint16_t*)wb, b1, b2,
                                            bias, (float*)d_out, NN);
}

// Round 11
// 226.182 us; speedup vs baseline: 1.1075x; 1.1075x over previous
//
#include <hip/hip_runtime.h>
#include <stdint.h>

// GIN conv: agg = segment_sum(val * x[col], row); h=(1+eps)x+agg;
// h=relu(h@W1+b1); h=relu(h@W2+b2); out=relu(h+bias).
// R13 = R10 restored (best verified: 229.1us). Both fusion directions
// empirically eliminated: R11 agg+mlp (+2.4us, barrier after variable-
// degree work); R12 bucket+agg (+21us, 392x1024 blocks collapse gather
// occupancy 70%->31%, HBM 3.9->2.3 TB/s). The 1563x256 k_agg launch
// granularity IS the performance. agg ~60us = ~13% over compulsory-miss
// fabric floor; ~127us/iter is harness reset.

static constexpr int NN = 100000;
static constexpr int NE = 1600000;
static constexpr int NB = 392;    // buckets of 256 rows
static constexpr int EPB = 4096;  // edges per partition block
static constexpr int PB = (NE + EPB - 1) / EPB;  // 391
static constexpr int BCAP = 8192; // per-bucket edge capacity (avg 4082)
static constexpr int NCVT = (NN * 32) / 1024;    // 3125 cvt blocks
static constexpr int NWB = 16;    // weight-convert blocks

typedef float f32x4 __attribute__((ext_vector_type(4)));
typedef short s16x8 __attribute__((ext_vector_type(8)));

__device__ __forceinline__ uint16_t f2bf(float f) {
  uint32_t u = __float_as_uint(f);
  u += 0x7fffu + ((u >> 16) & 1u);   // round-to-nearest-even
  return (uint16_t)(u >> 16);
}
__device__ __forceinline__ float2 bf2f(uint32_t w) {
  float2 r;
  r.x = __uint_as_float(w << 16);
  r.y = __uint_as_float(w & 0xffff0000u);
  return r;
}

// inclusive Hillis-Steele scan over first WIDTH entries of s0/s1.
// ALL threads of the block must call (barriers inside).
template <int WIDTH>
__device__ __forceinline__ int* scan_inc(int* s0, int* s1, int tid) {
  int* pin = s0;
  int* pout = s1;
  for (int off = 1; off < WIDTH; off <<= 1) {
    if (tid < WIDTH) pout[tid] = pin[tid] + ((tid >= off) ? pin[tid - off] : 0);
    __syncthreads();
    int* tmp = pin; pin = pout; pout = tmp;
  }
  return pin;
}

// ------- fused prep: [0,PB) edge partition | [PB,PB+NCVT) x->bf16 |
//         [PB+NCVT, +NWB) W1/W2 transpose->bf16 ---------------------------
__global__ __launch_bounds__(1024) void k_prep(const float* __restrict__ x,
                                               uint32_t* __restrict__ xb,
                                               const int* __restrict__ erow,
                                               const int* __restrict__ ecol,
                                               const float* __restrict__ eval,
                                               int2* __restrict__ part,
                                               int* __restrict__ runstart,
                                               const float* __restrict__ W1,
                                               const float* __restrict__ W2,
                                               uint32_t* __restrict__ wbp) {
  __shared__ int hist[NB];
  __shared__ int cur[NB];
  __shared__ int s0[512], s1[512];
  __shared__ int2 stage[EPB];
  int t = threadIdx.x;
  int bid = blockIdx.x;

  if (bid >= PB) {
    int cid = bid - PB;
    if (cid < NCVT) {
      // ---- x -> packed bf16 pairs ----
      int i = cid * 1024 + t;
      if (i < NN * 32) {
        float4 v = ((const float4*)x)[i];
        uint2 o;
        o.x = (uint32_t)f2bf(v.x) | ((uint32_t)f2bf(v.y) << 16);
        o.y = (uint32_t)f2bf(v.z) | ((uint32_t)f2bf(v.w) << 16);
        ((uint2*)xb)[i] = o;
      }
    } else {
      // ---- weight transpose: wb[m][n*128+k] = bf16(Wm[k*128+n]) ----
      int flat = (cid - NCVT) * 1024 + t;  // [0, 16384)
      int m = flat >> 13;                  // 0: W1, 1: W2
      int p = flat & 8191;
      int n = p >> 6;
      int k = (p & 63) * 2;
      const float* Wm = m ? W2 : W1;
      uint32_t lo = f2bf(Wm[k * 128 + n]);
      uint32_t hi = f2bf(Wm[(k + 1) * 128 + n]);
      wbp[(size_t)m * 8192 + n * 64 + (p & 63)] = lo | (hi << 16);
    }
    return;
  }

  // ---- edge partition into NB buckets (one block per EPB edges) ----
  int base = bid * EPB;
  int cnt = min(EPB, NE - base);

  if (t < NB) hist[t] = 0;
  __syncthreads();

  int pb[4], pk[4], pv[4];
  #pragma unroll
  for (int j = 0; j < 4; ++j) {
    int i = t + j * 1024;
    pb[j] = -1;
    if (i < cnt) {
      int e = base + i;
      int r = erow[e];
      int b = r >> 8;
      pb[j] = b;
      pk[j] = ecol[e] | ((r & 255) << 17);
      pv[j] = __float_as_int(eval[e]);
      atomicAdd(&hist[b], 1);
    }
  }
  __syncthreads();

  if (t < 512) s0[t] = (t < NB) ? hist[t] : 0;
  __syncthreads();
  int* inc = scan_inc<512>(s0, s1, t);

  if (t < NB) {
    int h = hist[t];
    int st = inc[t] - h;  // exclusive
    cur[t] = st;
    runstart[bid * (NB + 1) + t] = st;
  }
  if (t == 0) runstart[bid * (NB + 1) + NB] = cnt;
  __syncthreads();

  #pragma unroll
  for (int j = 0; j < 4; ++j) {
    if (pb[j] >= 0) {
      int off = atomicAdd(&cur[pb[j]], 1);
      stage[off] = int2{pk[j], pv[j]};
    }
  }
  __syncthreads();

  for (int i = t; i < cnt; i += 1024) part[base + i] = stage[i];
}

// ---------------- phase 2: per-bucket CSR (one block per bucket) -----------
// Fixed-stride output region: es[b*BCAP + local]. rowptr is 257-stride per
// bucket: [b*257+t] = start of row t, [b*257+256] = base+total (end sentinel).
__global__ __launch_bounds__(1024) void k_bucket(const int2* __restrict__ part,
                                                 const int* __restrict__ runstart,
                                                 int2* __restrict__ es,
                                                 int* __restrict__ rowptr) {
  __shared__ int cum[PB + 1];
  __shared__ int rbas[PB];
  __shared__ int hist[256];
  __shared__ int rps[256];
  __shared__ int cur[256];
  __shared__ int s0[512], s1[512];
  __shared__ int2 stage[BCAP];
  int b = blockIdx.x, t = threadIdx.x;
  int base_out = b * BCAP;

  int len = 0;
  if (t < PB) {
    int rs = runstart[t * (NB + 1) + b];
    int re = runstart[t * (NB + 1) + b + 1];
    len = re - rs;
    rbas[t] = t * EPB + rs;
  }
  __syncthreads();
  if (t < 512) s0[t] = (t < PB) ? len : 0;
  __syncthreads();
  int* inc1 = scan_inc<512>(s0, s1, t);
  if (t < PB) cum[t] = inc1[t] - len;
  if (t == 0) cum[PB] = inc1[PB - 1];
  if (t < 256) hist[t] = 0;
  __syncthreads();

  int total = cum[PB];

  // pass 1: gather edges (binary search run), histogram rows-in-bucket
  int pk[8], pv[8];
  #pragma unroll
  for (int j = 0; j < 8; ++j) {
    int s = t + j * 1024;
    pk[j] = -1;
    if (s < total) {
      int lo = 0, hi = PB;  // invariant: cum[lo] <= s < cum[hi]
      while (hi - lo > 1) {
        int mid = (lo + hi) >> 1;
        if (cum[mid] <= s) lo = mid; else hi = mid;
      }
      int2 ev = part[rbas[lo] + (s - cum[lo])];
      pk[j] = ev.x; pv[j] = ev.y;
      atomicAdd(&hist[ev.x >> 17], 1);
    }
  }
  __syncthreads();

  if (t < 256) s0[t] = hist[t];
  __syncthreads();
  int* inc2 = scan_inc<256>(s0, s1, t);
  if (t < 256) {
    int ex = inc2[t] - hist[t];
    rps[t] = ex;
    cur[t] = ex;
  }
  __syncthreads();

  if (t < 256) rowptr[b * 257 + t] = base_out + rps[t];
  if (t == 0)  rowptr[b * 257 + 256] = base_out + total;  // bucket end sentinel

  // pass 2: ticket-scatter into LDS stage (bucket-local offsets)
  #pragma unroll
  for (int j = 0; j < 8; ++j) {
    if (pk[j] >= 0) {
      int rib = pk[j] >> 17;
      int off = atomicAdd(&cur[rib], 1);
      int2 rec = int2{pk[j] & 0x1FFFF, pv[j]};
      if (off < BCAP) stage[off] = rec;
      else es[base_out + off] = rec;  // statistical never (needs total>8192)
    }
  }
  __syncthreads();

  // coalesced writeback of the bucket's contiguous es region
  for (int i = t; i < total; i += 1024) es[base_out + i] = stage[i];
}

// ---------------- aggregate: one wave per node, scalar edge stream ---------
// Edge records are wave-uniform -> readfirstlane forces them into SGPRs.
// 16-edge batches; masked slots reuse scol[0] (L1 same-line hit), sval=0.
// Tail reads extend <=14 entries into the bucket's own slack (in-bounds;
// values discarded by the live-mask). rowptr is 257-stride per bucket.
__global__ __launch_bounds__(256) void k_agg(const uint32_t* __restrict__ xb,
                                             const int2* __restrict__ es,
                                             const int* __restrict__ rowptr,
                                             const float* __restrict__ eps,
                                             uint32_t* __restrict__ hb) {
  int wid = (blockIdx.x * 256 + threadIdx.x) >> 6;
  int wave = __builtin_amdgcn_readfirstlane(wid);
  int lane = threadIdx.x & 63;
  float e = 1.0f + eps[0];
  float2 h = bf2f(xb[(size_t)wave * 64 + lane]);
  h.x *= e; h.y *= e;
  int rp = (wave >> 8) * 257 + (wave & 255);
  int beg = __builtin_amdgcn_readfirstlane(rowptr[rp]);
  int end = __builtin_amdgcn_readfirstlane(rowptr[rp + 1]);
  for (int k = beg; k < end; k += 16) {
    int scol[16]; float sval[16];
    {
      int2 ev0 = es[k];  // j=0 always live (k < end)
      scol[0] = __builtin_amdgcn_readfirstlane(ev0.x);
      sval[0] = __int_as_float(__builtin_amdgcn_readfirstlane(ev0.y));
    }
    #pragma unroll
    for (int j = 1; j < 16; ++j) {
      int2 ev = es[k + j];  // in-bucket slack; masked values discarded
      int c = __builtin_amdgcn_readfirstlane(ev.x);
      int vb = __builtin_amdgcn_readfirstlane(ev.y);
      bool live = (k + j < end);
      scol[j] = live ? c : scol[0];   // masked: same line as slot 0 -> L1 hit
      sval[j] = live ? __int_as_float(vb) : 0.0f;
    }
    uint32_t xw[16];
    #pragma unroll
    for (int j = 0; j < 16; ++j)
      xw[j] = xb[((size_t)scol[j] << 6) + lane];
    #pragma unroll
    for (int j = 0; j < 16; ++j) {
      float2 xv = bf2f(xw[j]);
      h.x = fmaf(sval[j], xv.x, h.x);
      h.y = fmaf(sval[j], xv.y, h.y);
    }
  }
  hb[(size_t)wave * 64 + lane] = (uint32_t)f2bf(h.x) | ((uint32_t)f2bf(h.y) << 16);
}

// ---------------- fused 2-layer MFMA MLP: [64,128] rows per block ----------
// out = relu(relu(relu(h@W1+b1)@W2+b2)+bias). Weights arrive pre-transposed
// bf16 (wb[n*128+k]); staged into LDS stride-136 with conflict-free 16B
// vector copies. Interlayer h1 kept in LDS bf16. 3 blocks/CU.
__global__ __launch_bounds__(256, 3) void k_mlp(const uint16_t* __restrict__ A,
                                                const uint16_t* __restrict__ wb,
                                                const float* __restrict__ b1,
                                                const float* __restrict__ b2,
                                                const float* __restrict__ bias,
                                                float* __restrict__ out, int nrows) {
  __shared__ uint16_t wt[128 * 136];
  __shared__ uint16_t h1[64 * 136];
  int tid = threadIdx.x;

  // stage W1^T (bf16): 2048 16B-chunks, 8 iters, conflict-free
  #pragma unroll
  for (int it = 0; it < 8; ++it) {
    int c = tid + it * 256;          // chunk id 0..2047
    int r = c >> 4, cc = c & 15;
    *(uint4*)&wt[r * 136 + cc * 8] = *(const uint4*)&wb[r * 128 + cc * 8];
  }
  __syncthreads();

  int wv = tid >> 6, l = tid & 63;
  int m16 = l & 15, qg = l >> 4;
  int r0 = blockIdx.x * 64 + wv * 16;  // wave's 16-row tile
  int arow = r0 + m16;
  if (arow >= nrows) arow = nrows - 1;  // clamp; stores guarded

  f32x4 acc[8];
  #pragma unroll
  for (int n0 = 0; n0 < 8; ++n0) acc[n0] = f32x4{0.f, 0.f, 0.f, 0.f};

  #pragma unroll
  for (int k0 = 0; k0 < 128; k0 += 32) {
    s16x8 a = *(const s16x8*)(A + (size_t)arow * 128 + k0 + qg * 8);
    #pragma unroll
    for (int n0 = 0; n0 < 8; ++n0) {
      s16x8 bfr = *(const s16x8*)(&wt[(n0 * 16 + m16) * 136 + k0 + qg * 8]);
      acc[n0] = __builtin_amdgcn_mfma_f32_16x16x32_bf16(a, bfr, acc[n0], 0, 0, 0);
    }
  }

  // epilogue 1: relu(acc + b1) -> h1 LDS (bf16). C/D: col=lane&15, row=qg*4+j
  #pragma unroll
  for (int n0 = 0; n0 < 8; ++n0) {
    int col = n0 * 16 + m16;
    float bb = b1[col];
    #pragma unroll
    for (int j = 0; j < 4; ++j) {
      int lr = wv * 16 + qg * 4 + j;
      h1[lr * 136 + col] = f2bf(fmaxf(acc[n0][j] + bb, 0.0f));
    }
  }
  __syncthreads();

  // stage W2^T
  #pragma unroll
  for (int it = 0; it < 8; ++it) {
    int c = tid + it * 256;
    int r = c >> 4, cc = c & 15;
    *(uint4*)&wt[r * 136 + cc * 8] = *(const uint4*)&wb[16384 + r * 128 + cc * 8];
  }
  #pragma unroll
  for (int n0 = 0; n0 < 8; ++n0) acc[n0] = f32x4{0.f, 0.f, 0.f, 0.f};
  __syncthreads();

  #pragma unroll
  for (int k0 = 0; k0 < 128; k0 += 32) {
    s16x8 a = *(const s16x8*)(&h1[(wv * 16 + m16) * 136 + k0 + qg * 8]);
    #pragma unroll
    for (int n0 = 0; n0 < 8; ++n0) {
      s16x8 bfr = *(const s16x8*)(&wt[(n0 * 16 + m16) * 136 + k0 + qg * 8]);
      acc[n0] = __builtin_amdgcn_mfma_f32_16x16x32_bf16(a, bfr, acc[n0], 0, 0, 0);
    }
  }

  // epilogue 2: relu(relu(acc + b2) + bias) -> out (fp32)
  #pragma unroll
  for (int n0 = 0; n0 < 8; ++n0) {
    int col = n0 * 16 + m16;
    float bb = b2[col];
    float b3 = bias[col];
    #pragma unroll
    for (int j = 0; j < 4; ++j) {
      int row = r0 + qg * 4 + j;
      if (row < nrows) {
        float v = fmaxf(fmaxf(acc[n0][j] + bb, 0.0f) + b3, 0.0f);
        out[(size_t)row * 128 + col] = v;
      }
    }
  }
}

extern "C" void kernel_launch(void* const* d_in, const int* in_sizes, int n_in,
                              void* d_out, int out_size, void* d_ws, size_t ws_size,
                              hipStream_t stream) {
  const float* x    = (const float*)d_in[0];
  const int*   erow = (const int*)d_in[1];
  const int*   ecol = (const int*)d_in[2];
  const float* eval = (const float*)d_in[3];
  const float* W1   = (const float*)d_in[4];
  const float* b1   = (const float*)d_in[5];
  const float* W2   = (const float*)d_in[6];
  const float* b2   = (const float*)d_in[7];
  const float* eps  = (const float*)d_in[8];
  const float* bias = (const float*)d_in[9];

  char* w = (char*)d_ws;
  size_t off = 0;
  auto take = [&](size_t bytes) -> void* {
    void* p = w + off;
    off = (off + bytes + 255) & ~(size_t)255;
    return p;
  };
  uint32_t* xb     = (uint32_t*)take((size_t)NN * 64 * 4);   // bf16 x, packed
  uint32_t* hb     = (uint32_t*)take((size_t)NN * 64 * 4);   // bf16 h, packed
  int2*     part   = (int2*)take((size_t)NE * 8);
  int2*     es     = (int2*)take((size_t)(NB * BCAP + 16) * 8); // fixed-stride CSR
  int*      rowptr = (int*)take((size_t)(NB * 257) * 4);     // 257-stride/bucket
  int*      runst  = (int*)take((size_t)PB * (NB + 1) * 4);
  uint32_t* wb     = (uint32_t*)take((size_t)2 * 8192 * 4);  // W1^T,W2^T bf16
  (void)ws_size;

  k_prep<<<PB + NCVT + NWB, 1024, 0, stream>>>(x, xb, erow, ecol, eval, part,
                                               runst, W1, W2, wb);
  k_bucket<<<NB, 1024, 0, stream>>>(part, runst, es, rowptr);
  k_agg<<<(NN + 3) / 4, 256, 0, stream>>>(xb, es, rowptr, eps, hb);
  k_mlp<<<(NN + 63) / 64, 256, 0, stream>>>((const uint16_t*)hb,
                                            (const uint16_t*)wb, b1, b2,
                                            bias, (float*)d_out, NN);
}